// Round 4
// baseline (1043.941 us; speedup 1.0000x reference)
//
#include <hip/hip_runtime.h>
#include <hip/hip_bf16.h>
#include <cstdint>
#include <cstddef>

namespace {

constexpr int BATCH = 16;
constexpr int LEN   = 8192;
constexpr int CIN   = 257;
constexpr int CS    = 256;   // space channels
constexpr int NF    = 4096;  // output frames
constexpr int KG    = 1280;  // GEMM K (5 taps * 256 ch), time handled as rank-1
constexpr int MT    = 128;   // frames per block
constexpr int NITER = 20;    // K iterations of 64

// workspace layout: only bf16 W transpose + w0 column. ~0.66 MB.
constexpr size_t WT_BYTES = (size_t)CS * KG * 2;      // 655,360
constexpr size_t W0_OFF   = WT_BYTES;
constexpr size_t WS_NEED  = W0_OFF + (size_t)CS * 4;  // ~656.4 KB

typedef __attribute__((ext_vector_type(8))) short short8;
typedef __attribute__((ext_vector_type(4))) float f32x4;

union bfpack { unsigned short u[8]; short8 s; };

__device__ __forceinline__ unsigned short f2bf_bits(float f) {
  union { __hip_bfloat16 h; unsigned short u; } cv;
  cv.h = __float2bfloat16(f);
  return cv.u;
}

} // namespace

// ---------------- prep: W (257x1281 f32) -> wt bf16 [256][1280] + w0[256] f32
__global__ void prep_w_kernel(const float* __restrict__ W,
                              __hip_bfloat16* __restrict__ wt,
                              float* __restrict__ w0) {
  int n = blockIdx.x;                    // 0..255 -> out channel n+1
  const float* wrow = W + (size_t)(n + 1) * 1281;
  for (int k = threadIdx.x; k < KG; k += blockDim.x)
    wt[(size_t)n * KG + k] = __float2bfloat16(wrow[1 + k]);
  if (threadIdx.x == 0) w0[n] = wrow[0];
}

// ---------------- fused GEMM, LDS-free / barrier-free K-loop.
// B (wt, 640 KB) is L2-resident: each wave loads its MFMA B-fragments as
// short8 straight from global (bit-identical to the LDS path). A comes from
// x (135 MB, L3-resident): f32 loads -> in-reg bf16 cvt + sumsq, ping-pong
// register prefetch one K-iter ahead. No __syncthreads until the epilogue,
// so waves latency-hide each other freely (16 waves/CU, 2 blocks/CU).
// block: 512 threads = 8 waves; wave (wm = w>>1, wn = w&1) computes 32x128.
__global__ __launch_bounds__(512, 4) void lorentz_fused_kernel(
    const float* __restrict__ x,
    const __hip_bfloat16* __restrict__ wt,
    const float* __restrict__ w0,
    const float* __restrict__ bvec,
    float* __restrict__ out) {
  __shared__ alignas(16) float time0_s[128];
  __shared__ alignas(16) float normsq_s[128];

  const int tid   = threadIdx.x;
  const int w     = tid >> 6;   // 0..7
  const int lane  = tid & 63;
  const int row16 = lane & 15;
  const int q     = lane >> 4;  // 0..3
  const int wm    = w >> 1;     // 0..3  M 32-row strip
  const int wn    = w & 1;      // 0..1  N 128-col half

  const int bx    = blockIdx.x;
  const int b     = bx >> 5;          // 32 M-blocks per batch
  const int Mblk  = (bx & 31) * MT;

  const float* xb = x + (size_t)b * LEN * CIN;
  const int frame0 = Mblk + wm * 32 + row16;   // + mt*16 -> output frame

  f32x4 acc[2][8];
#pragma unroll
  for (int i = 0; i < 2; ++i)
#pragma unroll
    for (int j = 0; j < 8; ++j) acc[i][j] = (f32x4){0.f, 0.f, 0.f, 0.f};

  // A in-flight f32 regs: [mt][s*2+half] (8 x f32x4 per bank)
  f32x4 afA[2][4], afB[2][4];
  float ssq0 = 0.f, ssq1 = 0.f;

  auto loadA = [&](int it, f32x4 (&af)[2][4]) {
#pragma unroll
    for (int mt = 0; mt < 2; ++mt) {
      const int t = 2 * (frame0 + mt * 16) + (it >> 2) - 2;
      af[mt][0] = (f32x4){0.f, 0.f, 0.f, 0.f};
      af[mt][1] = af[mt][0];
      af[mt][2] = af[mt][0];
      af[mt][3] = af[mt][0];
      if ((unsigned)t < (unsigned)LEN) {
        const float* g = xb + (size_t)t * CIN + 1 + ((it & 3) << 6) + q * 8;
        __builtin_memcpy(&af[mt][0], g, 16);
        __builtin_memcpy(&af[mt][1], g + 4, 16);
        __builtin_memcpy(&af[mt][2], g + 32, 16);
        __builtin_memcpy(&af[mt][3], g + 36, 16);
      }
    }
  };

  auto cvt2 = [&](const f32x4& lo, const f32x4& hi) -> short8 {
    bfpack p;
#pragma unroll
    for (int i = 0; i < 4; ++i) {
      p.u[i]     = f2bf_bits(lo[i]);
      p.u[4 + i] = f2bf_bits(hi[i]);
    }
    return p.s;
  };

  // one K=32 half: load 8 B-frags from L2-hot wt, cvt A, 16 MFMAs
  auto mfma_half = [&](int it, int s, f32x4 (&cur)[2][4]) {
    const int ko = (it << 6) + s * 32 + q * 8;
    short8 bb[8];
#pragma unroll
    for (int nt = 0; nt < 8; ++nt) {
      const int n = wn * 128 + nt * 16 + row16;
      bb[nt] = *(const short8*)(wt + (size_t)n * KG + ko);
    }
    short8 ab0 = cvt2(cur[0][s * 2], cur[0][s * 2 + 1]);
    short8 ab1 = cvt2(cur[1][s * 2], cur[1][s * 2 + 1]);
    if (wn == 0) {   // count each patch element exactly once
#pragma unroll
      for (int i = 0; i < 4; ++i) {
        ssq0 += cur[0][s*2][i] * cur[0][s*2][i] + cur[0][s*2+1][i] * cur[0][s*2+1][i];
        ssq1 += cur[1][s*2][i] * cur[1][s*2][i] + cur[1][s*2+1][i] * cur[1][s*2+1][i];
      }
    }
#pragma unroll
    for (int nt = 0; nt < 8; ++nt) {
      acc[0][nt] = __builtin_amdgcn_mfma_f32_16x16x32_bf16(ab0, bb[nt], acc[0][nt], 0, 0, 0);
      acc[1][nt] = __builtin_amdgcn_mfma_f32_16x16x32_bf16(ab1, bb[nt], acc[1][nt], 0, 0, 0);
    }
  };

  auto body = [&](int it, f32x4 (&cur)[2][4], f32x4 (&nxt)[2][4]) {
    if (it + 1 < NITER) loadA(it + 1, nxt);   // prefetch next A (L3 latency)
    mfma_half(it, 0, cur);
    mfma_half(it, 1, cur);
  };

  loadA(0, afA);
  for (int it = 0; it < NITER; it += 2) {
    body(it,     afA, afB);
    body(it + 1, afB, afA);
  }

  // ---- epilogue: time0 (from in-register sumsq) + bias, renorm, store -----
  if (tid < 128) normsq_s[tid] = 0.0f;
  {
    float s0 = ssq0; s0 += __shfl_xor(s0, 16); s0 += __shfl_xor(s0, 32);
    float s1 = ssq1; s1 += __shfl_xor(s1, 16); s1 += __shfl_xor(s1, 32);
    if (wn == 0 && q == 0) {
      time0_s[wm * 32 + row16]      = sqrtf(1.0f + s0);
      time0_s[wm * 32 + 16 + row16] = sqrtf(1.0f + s1);
    }
  }
  __syncthreads();

  float w0v[8], bv[8];
#pragma unroll
  for (int nt = 0; nt < 8; ++nt) {
    int n = wn * 128 + nt * 16 + row16;
    w0v[nt] = w0[n];
    bv[nt]  = bvec[1 + n];
  }

#pragma unroll
  for (int mt = 0; mt < 2; ++mt) {
    f32x4 t4 = *(const f32x4*)&time0_s[wm * 32 + mt * 16 + q * 4];
#pragma unroll
    for (int nt = 0; nt < 8; ++nt)
#pragma unroll
      for (int r = 0; r < 4; ++r)
        acc[mt][nt][r] = acc[mt][nt][r] + t4[r] * w0v[nt] + bv[nt];
#pragma unroll
    for (int r = 0; r < 4; ++r) {
      float ps = 0.f;
#pragma unroll
      for (int nt = 0; nt < 8; ++nt) ps += acc[mt][nt][r] * acc[mt][nt][r];
      ps += __shfl_xor(ps, 1);
      ps += __shfl_xor(ps, 2);
      ps += __shfl_xor(ps, 4);
      ps += __shfl_xor(ps, 8);
      if (row16 == 0) atomicAdd(&normsq_s[wm * 32 + mt * 16 + q * 4 + r], ps);
    }
  }
  __syncthreads();

#pragma unroll
  for (int mt = 0; mt < 2; ++mt) {
#pragma unroll
    for (int r = 0; r < 4; ++r) {
      int m = wm * 32 + mt * 16 + q * 4 + r;
      float nsq  = normsq_s[m];
      float norm = sqrtf(nsq);
      float scale = fminf(1.0f, 1000.0f / fmaxf(norm, 1e-8f));
      size_t ob = ((size_t)b * NF + Mblk + m) * 257;
#pragma unroll
      for (int nt = 0; nt < 8; ++nt)
        out[ob + 1 + wn * 128 + nt * 16 + row16] = acc[mt][nt][r] * scale;
    }
  }
  if (tid < 128) {
    float nsq  = normsq_s[tid];
    float norm = sqrtf(nsq);
    float scale = fminf(1.0f, 1000.0f / fmaxf(norm, 1e-8f));
    size_t ob = ((size_t)b * NF + Mblk + tid) * 257;
    out[ob] = sqrtf(1.0f + scale * scale * nsq);
  }
}

// ---------------- safety fallback (only if ws < ~0.66 MB): naive fp32
__global__ void fallback_kernel(const float* __restrict__ x,
                                const float* __restrict__ W,
                                const float* __restrict__ bvec,
                                float* __restrict__ out) {
  int fid = blockIdx.x;
  int b = fid >> 12;
  int g = fid & (NF - 1);
  __shared__ float patch[1280];
  __shared__ float red[256];
  int tid = threadIdx.x;
  float ss = 0.f;
  for (int k = tid; k < 1280; k += 256) {
    int kk = k >> 8, c = k & 255;
    int t = 2 * g + kk - 2;
    float v = (t >= 0 && t < LEN) ? x[((size_t)b * LEN + t) * CIN + 1 + c] : 0.f;
    patch[k] = v;
    ss += v * v;
  }
  red[tid] = ss;
  __syncthreads();
  for (int off = 128; off > 0; off >>= 1) {
    if (tid < off) red[tid] += red[tid + off];
    __syncthreads();
  }
  float time0 = sqrtf(1.f + red[0]);
  __syncthreads();
  const float* wrow = W + (size_t)(tid + 1) * 1281;
  float acc = time0 * wrow[0] + bvec[tid + 1];
  for (int k = 0; k < 1280; ++k) acc += wrow[1 + k] * patch[k];
  red[tid] = acc * acc;
  __syncthreads();
  for (int off = 128; off > 0; off >>= 1) {
    if (tid < off) red[tid] += red[tid + off];
    __syncthreads();
  }
  float nsq = red[0];
  float norm = sqrtf(nsq);
  float scale = fminf(1.f, 1000.f / fmaxf(norm, 1e-8f));
  size_t ob = ((size_t)b * NF + g) * 257;
  out[ob + 1 + tid] = acc * scale;
  if (tid == 0) out[ob] = sqrtf(1.f + scale * scale * nsq);
}

extern "C" void kernel_launch(void* const* d_in, const int* in_sizes, int n_in,
                              void* d_out, int out_size, void* d_ws, size_t ws_size,
                              hipStream_t stream) {
  const float* x  = (const float*)d_in[0];
  const float* W  = (const float*)d_in[1];
  const float* bv = (const float*)d_in[2];
  float* out = (float*)d_out;

  if (ws_size >= WS_NEED) {
    char* ws = (char*)d_ws;
    __hip_bfloat16* wt = (__hip_bfloat16*)ws;
    float* w0          = (float*)(ws + W0_OFF);
    prep_w_kernel<<<256, 256, 0, stream>>>(W, wt, w0);
    lorentz_fused_kernel<<<BATCH * (NF / MT), 512, 0, stream>>>(x, wt, w0, bv, out);
  } else {
    fallback_kernel<<<BATCH * NF, 256, 0, stream>>>(x, W, bv, out);
  }
}

// Round 5
// 277.075 us; speedup vs baseline: 3.7677x; 3.7677x over previous
//
#include <hip/hip_runtime.h>
#include <hip/hip_bf16.h>
#include <cstdint>
#include <cstddef>

namespace {

constexpr int BATCH = 16;
constexpr int LEN   = 8192;
constexpr int CIN   = 257;
constexpr int CS    = 256;   // space channels
constexpr int NF    = 4096;  // output frames
constexpr int KG    = 1280;  // GEMM K (5 taps * 256 ch), time handled as rank-1
constexpr int MT    = 128;   // frames per block
constexpr int NITER = 20;    // K iterations of 64

// workspace layout: only bf16 W transpose + w0 column. ~0.66 MB.
constexpr size_t WT_BYTES = (size_t)CS * KG * 2;      // 655,360
constexpr size_t W0_OFF   = WT_BYTES;
constexpr size_t WS_NEED  = W0_OFF + (size_t)CS * 4;  // ~656.4 KB

typedef __attribute__((ext_vector_type(8))) short short8;
typedef __attribute__((ext_vector_type(8))) unsigned short ushort8v;
typedef __attribute__((ext_vector_type(4))) float f32x4;

struct ARegs { f32x4 a00, a01, a10, a11; };   // 16 floats / bank

__device__ __forceinline__ unsigned short f2bf_bits(float f) {
  union { __hip_bfloat16 h; unsigned short u; } cv;
  cv.h = __float2bfloat16(f);
  return cv.u;
}

__device__ __forceinline__ void async_cp16(const void* g, void* l) {
  __builtin_amdgcn_global_load_lds(
      (const __attribute__((address_space(1))) void*)g,
      (__attribute__((address_space(3))) void*)l,
      16, 0, 0);
}

} // namespace

// ---------------- prep: W (257x1281 f32) -> wt bf16 [256][1280] + w0[256] f32
__global__ void prep_w_kernel(const float* __restrict__ W,
                              __hip_bfloat16* __restrict__ wt,
                              float* __restrict__ w0) {
  int n = blockIdx.x;                    // 0..255 -> out channel n+1
  const float* wrow = W + (size_t)(n + 1) * 1281;
  for (int k = threadIdx.x; k < KG; k += blockDim.x)
    wt[(size_t)n * KG + k] = __float2bfloat16(wrow[1 + k]);
  if (threadIdx.x == 0) w0[n] = wrow[0];
}

// ---------------- fused GEMM: [128 frames] x [256 out ch], K=1280, bf16 MFMA
// T3/T4 schedule: B triple-buffered, staged 2 iters ahead via global_load_lds;
// A reg-staged depth-2 (f32->bf16 cvt + sumsq in flight), LDS double-buffered.
// ONE barrier per K-iter; per-iter s_waitcnt vmcnt(4) (never 0 in steady
// state) so the newest B-stage stays in flight across the barrier. setprio
// around MFMA clusters. block: 512 thr = 8 waves; wave (mh,nq) owns 64x64.
__global__ __launch_bounds__(512, 2) void lorentz_fused_kernel(
    const float* __restrict__ x,
    const __hip_bfloat16* __restrict__ wt,
    const float* __restrict__ w0,
    const float* __restrict__ bvec,
    float* __restrict__ out) {
  __shared__ alignas(16) char Ab[2][16384];   // A: 128x64 bf16, dbuf
  __shared__ alignas(16) char Bb[3][32768];   // B: 256x64 bf16, TRIPLE buf
  __shared__ alignas(16) float time0_s[128];
  __shared__ alignas(16) float normsq_s[128];

  const int tid   = threadIdx.x;
  const int w     = tid >> 6;   // 0..7
  const int lane  = tid & 63;
  const int row16 = lane & 15;
  const int q     = lane >> 4;
  const int mh    = w >> 2;     // 0..1  M-half (64 rows)
  const int nq    = w & 3;      // 0..3  N-quarter (64 cols)
  const int lg    = lane >> 3;  // 0..7 row-in-group for staging
  const int lc    = lane & 7;   // chunk index for staging
  const int csw   = lc ^ lg;    // XOR swizzle (pos = chunk ^ (row&7))

  const int bx    = blockIdx.x;
  const int b     = bx >> 5;          // 32 M-blocks per batch
  const int Mblk  = (bx & 31) * MT;

  const int m0 = w * 16 + lg;      // staged frame row, j=0
  const int m1 = m0 + 8;           // staged frame row, j=1
  const float* xb = x + (size_t)b * LEN * CIN;

  f32x4 acc[4][4];
#pragma unroll
  for (int i = 0; i < 4; ++i)
#pragma unroll
    for (int j = 0; j < 4; ++j) acc[i][j] = (f32x4){0.f, 0.f, 0.f, 0.f};

  ARegs afE, afO;                  // depth-2 A register banks
  float ssq0 = 0.f, ssq1 = 0.f;

  // ---- helpers (addressing identical to the verified R1 kernel) ----------
  auto loadA = [&](int it, ARegs& af) {
    const int kk = it >> 2;
    const int c0 = (it & 3) << 6;
    const int coff = 1 + c0 + lc * 8;
    const int t0 = 2 * (Mblk + m0) + kk - 2;
    const int t1 = t0 + 16;
    af.a00 = (f32x4){0.f, 0.f, 0.f, 0.f};
    af.a01 = af.a00; af.a10 = af.a00; af.a11 = af.a00;
    if ((unsigned)t0 < (unsigned)LEN) {
      const float* g = xb + (size_t)t0 * CIN + coff;
      __builtin_memcpy(&af.a00, g, 16);
      __builtin_memcpy(&af.a01, g + 4, 16);
    }
    if ((unsigned)t1 < (unsigned)LEN) {
      const float* g = xb + (size_t)t1 * CIN + coff;
      __builtin_memcpy(&af.a10, g, 16);
      __builtin_memcpy(&af.a11, g + 4, 16);
    }
  };

  auto writeA = [&](char* A, ARegs& af) {
    ssq0 += af.a00[0]*af.a00[0] + af.a00[1]*af.a00[1] + af.a00[2]*af.a00[2] + af.a00[3]*af.a00[3]
          + af.a01[0]*af.a01[0] + af.a01[1]*af.a01[1] + af.a01[2]*af.a01[2] + af.a01[3]*af.a01[3];
    ssq1 += af.a10[0]*af.a10[0] + af.a10[1]*af.a10[1] + af.a10[2]*af.a10[2] + af.a10[3]*af.a10[3]
          + af.a11[0]*af.a11[0] + af.a11[1]*af.a11[1] + af.a11[2]*af.a11[2] + af.a11[3]*af.a11[3];
    ushort8v u0, u1;
#pragma unroll
    for (int i = 0; i < 4; ++i) {
      u0[i]     = f2bf_bits(af.a00[i]);
      u0[4 + i] = f2bf_bits(af.a01[i]);
      u1[i]     = f2bf_bits(af.a10[i]);
      u1[4 + i] = f2bf_bits(af.a11[i]);
    }
    *(ushort8v*)(A + ((m0 * 8 + csw) << 4)) = u0;
    *(ushort8v*)(A + ((m1 * 8 + csw) << 4)) = u1;
  };

  auto stageB = [&](int it, char* B) {
    const int k0 = it << 6;
#pragma unroll
    for (int j = 0; j < 4; ++j) {
      const int n = w * 32 + j * 8 + lg;
      async_cp16(wt + (size_t)n * KG + k0 + csw * 8, B + (w * 4 + j) * 1024);
    }
  };

  auto mfma_s = [&](const char* A, const char* B, int s) {
    const int p = (s * 4 + q) ^ lc;  // un-swizzle: pos = chunk ^ (row&7)
    short8 bfr[4];
#pragma unroll
    for (int nt = 0; nt < 4; ++nt)
      bfr[nt] = *(const short8*)(B + (((nq * 64 + nt * 16 + row16) * 8 + p) << 4));
    __builtin_amdgcn_s_setprio(1);
#pragma unroll
    for (int mt = 0; mt < 4; ++mt) {
      short8 af = *(const short8*)(A + (((mh * 64 + mt * 16 + row16) * 8 + p) << 4));
#pragma unroll
      for (int nt = 0; nt < 4; ++nt)
        acc[mt][nt] = __builtin_amdgcn_mfma_f32_16x16x32_bf16(
            af, bfr[nt], acc[mt][nt], 0, 0, 0);
    }
    __builtin_amdgcn_s_setprio(0);
  };

  // ---- prologue: tile0 resident; A(1),B(1) in flight ----------------------
  stageB(0, Bb[0]);
  loadA(0, afE);
  asm volatile("s_waitcnt vmcnt(0)" ::: "memory");   // one full drain, once
  writeA(Ab[0], afE);
  loadA(1, afO);
  stageB(1, Bb[1]);
  asm volatile("s_waitcnt lgkmcnt(0)" ::: "memory");
  asm volatile("" ::: "memory");
  __builtin_amdgcn_s_barrier();
  asm volatile("" ::: "memory");

  // ---- main loop: 1 barrier/iter, counted vmcnt ---------------------------
  auto iterBody = [&](int it, ARegs& regsC, ARegs& regsF) {
    char* Acur = Ab[it & 1];
    char* Anxt = Ab[(it + 1) & 1];
    char* Bcur = Bb[it % 3];
    // P1: issue far B-stage, then compute s=0 on current tile
    if (it + 2 < NITER) stageB(it + 2, Bb[(it + 2) % 3]);
    mfma_s(Acur, Bcur, 0);
    // P2: settle next tile (A write + B landed), issue far A loads, s=1
    if (it + 2 < NITER) {
      asm volatile("s_waitcnt vmcnt(4)" ::: "memory");  // A(it+1) regs + B(it+1) done
    } else if (it + 1 < NITER) {
      asm volatile("s_waitcnt vmcnt(0)" ::: "memory");  // tail drain
    }
    if (it + 1 < NITER) writeA(Anxt, regsC);
    if (it + 2 < NITER) loadA(it + 2, regsF);
    mfma_s(Acur, Bcur, 1);
    if (it + 1 < NITER) {
      asm volatile("s_waitcnt lgkmcnt(0)" ::: "memory");
      asm volatile("" ::: "memory");
      __builtin_amdgcn_s_barrier();
      asm volatile("" ::: "memory");
    }
  };

  for (int it = 0; it < NITER; it += 2) {
    iterBody(it,     afO, afE);   // consume regs(it+1)=odd bank, fill even
    iterBody(it + 1, afE, afO);   // consume even, fill odd
  }

  // ---- epilogue: time0 (from in-register sumsq) + bias, renorm, store -----
  __syncthreads();
  if (tid < 128) normsq_s[tid] = 0.0f;
  {
    float s0 = ssq0;
    s0 += __shfl_xor(s0, 1); s0 += __shfl_xor(s0, 2); s0 += __shfl_xor(s0, 4);
    float s1 = ssq1;
    s1 += __shfl_xor(s1, 1); s1 += __shfl_xor(s1, 2); s1 += __shfl_xor(s1, 4);
    if (lc == 0) {
      time0_s[m0] = sqrtf(1.0f + s0);
      time0_s[m1] = sqrtf(1.0f + s1);
    }
  }
  __syncthreads();

  float w0v[4], bv[4];
#pragma unroll
  for (int nt = 0; nt < 4; ++nt) {
    int n = nq * 64 + nt * 16 + row16;
    w0v[nt] = w0[n];
    bv[nt]  = bvec[1 + n];
  }

#pragma unroll
  for (int mt = 0; mt < 4; ++mt) {
    f32x4 t4 = *(const f32x4*)&time0_s[mh * 64 + mt * 16 + q * 4];
#pragma unroll
    for (int nt = 0; nt < 4; ++nt)
#pragma unroll
      for (int r = 0; r < 4; ++r)
        acc[mt][nt][r] = acc[mt][nt][r] + t4[r] * w0v[nt] + bv[nt];
#pragma unroll
    for (int r = 0; r < 4; ++r) {
      float ps = 0.f;
#pragma unroll
      for (int nt = 0; nt < 4; ++nt) ps += acc[mt][nt][r] * acc[mt][nt][r];
      ps += __shfl_xor(ps, 1);
      ps += __shfl_xor(ps, 2);
      ps += __shfl_xor(ps, 4);
      ps += __shfl_xor(ps, 8);
      if (row16 == 0) atomicAdd(&normsq_s[mh * 64 + mt * 16 + q * 4 + r], ps);
    }
  }
  __syncthreads();

#pragma unroll
  for (int mt = 0; mt < 4; ++mt) {
#pragma unroll
    for (int r = 0; r < 4; ++r) {
      int m = mh * 64 + mt * 16 + q * 4 + r;
      float nsq  = normsq_s[m];
      float norm = sqrtf(nsq);
      float scale = fminf(1.0f, 1000.0f / fmaxf(norm, 1e-8f));
      size_t ob = ((size_t)b * NF + Mblk + m) * 257;
#pragma unroll
      for (int nt = 0; nt < 4; ++nt) {
        int n = nq * 64 + nt * 16 + row16;
        out[ob + 1 + n] = acc[mt][nt][r] * scale;
      }
    }
  }
  if (tid < 128) {
    float nsq  = normsq_s[tid];
    float norm = sqrtf(nsq);
    float scale = fminf(1.0f, 1000.0f / fmaxf(norm, 1e-8f));
    size_t ob = ((size_t)b * NF + Mblk + tid) * 257;
    out[ob] = sqrtf(1.0f + scale * scale * nsq);
  }
}

// ---------------- safety fallback (only if ws < ~0.66 MB): naive fp32
__global__ void fallback_kernel(const float* __restrict__ x,
                                const float* __restrict__ W,
                                const float* __restrict__ bvec,
                                float* __restrict__ out) {
  int fid = blockIdx.x;
  int b = fid >> 12;
  int g = fid & (NF - 1);
  __shared__ float patch[1280];
  __shared__ float red[256];
  int tid = threadIdx.x;
  float ss = 0.f;
  for (int k = tid; k < 1280; k += 256) {
    int kk = k >> 8, c = k & 255;
    int t = 2 * g + kk - 2;
    float v = (t >= 0 && t < LEN) ? x[((size_t)b * LEN + t) * CIN + 1 + c] : 0.f;
    patch[k] = v;
    ss += v * v;
  }
  red[tid] = ss;
  __syncthreads();
  for (int off = 128; off > 0; off >>= 1) {
    if (tid < off) red[tid] += red[tid + off];
    __syncthreads();
  }
  float time0 = sqrtf(1.f + red[0]);
  __syncthreads();
  const float* wrow = W + (size_t)(tid + 1) * 1281;
  float acc = time0 * wrow[0] + bvec[tid + 1];
  for (int k = 0; k < 1280; ++k) acc += wrow[1 + k] * patch[k];
  red[tid] = acc * acc;
  __syncthreads();
  for (int off = 128; off > 0; off >>= 1) {
    if (tid < off) red[tid] += red[tid + off];
    __syncthreads();
  }
  float nsq = red[0];
  float norm = sqrtf(nsq);
  float scale = fminf(1.f, 1000.f / fmaxf(norm, 1e-8f));
  size_t ob = ((size_t)b * NF + g) * 257;
  out[ob + 1 + tid] = acc * scale;
  if (tid == 0) out[ob] = sqrtf(1.f + scale * scale * nsq);
}

extern "C" void kernel_launch(void* const* d_in, const int* in_sizes, int n_in,
                              void* d_out, int out_size, void* d_ws, size_t ws_size,
                              hipStream_t stream) {
  const float* x  = (const float*)d_in[0];
  const float* W  = (const float*)d_in[1];
  const float* bv = (const float*)d_in[2];
  float* out = (float*)d_out;

  if (ws_size >= WS_NEED) {
    char* ws = (char*)d_ws;
    __hip_bfloat16* wt = (__hip_bfloat16*)ws;
    float* w0          = (float*)(ws + W0_OFF);
    prep_w_kernel<<<256, 256, 0, stream>>>(W, wt, w0);
    lorentz_fused_kernel<<<BATCH * (NF / MT), 512, 0, stream>>>(x, wt, w0, bv, out);
  } else {
    fallback_kernel<<<BATCH * NF, 256, 0, stream>>>(x, W, bv, out);
  }
}